// Round 3
// baseline (111.389 us; speedup 1.0000x reference)
//
#include <hip/hip_runtime.h>

// out[1024][1024] = relu(a @ feats^T) @ relu(b @ feats^T)^T
//   a,b: [1024][2048] fp32, feats: [128][2048] fp32, out fp32.
// Pipeline: 2 kernels, no split-K, no atomics, no partials, no memset.
//   gemm1_full: 64 blocks; block bid owns rows [bid*32, bid*32+32) of [a;b]
//               and the FULL K=2048, accumulating 32x128 in registers; writes
//               relu'd bf16 fk[2048][128] directly (512 KB).
//   gemm2     : 512 blocks; 64x32 out tiles via MFMA on bf16 fk.

typedef __attribute__((ext_vector_type(8))) __bf16 bf16x8;
typedef __attribute__((ext_vector_type(4))) __bf16 bf16x4;
typedef __attribute__((ext_vector_type(4))) float floatx4;

#define KD     2048   // inner K of gemm1
#define NF     128    // feature count = K of gemm2
#define NA     1024   // rows of a (= rows of b = out dim)

static __device__ inline bf16x8 cvt8(float4 u, float4 v) {
    bf16x8 s;
    s[0] = (__bf16)u.x; s[1] = (__bf16)u.y; s[2] = (__bf16)u.z; s[3] = (__bf16)u.w;
    s[4] = (__bf16)v.x; s[5] = (__bf16)v.y; s[6] = (__bf16)v.z; s[7] = (__bf16)v.w;
    return s;
}

static __device__ inline bf16x4 cvt4(float4 u) {
    bf16x4 s;
    s[0] = (__bf16)u.x; s[1] = (__bf16)u.y; s[2] = (__bf16)u.z; s[3] = (__bf16)u.w;
    return s;
}

// ---- gemm1_full: fk[m0:m0+32][0:128] = relu( X[m0:m0+32, :] . feats^T ), bf16
// grid 64: bid = 32-row stripe of [a;b]. block = 4 waves; wave w covers
// feat-cols [w*32, w*32+32). Full K=2048 accumulated in registers.
__global__ __launch_bounds__(256) void gemm1_full(const float* __restrict__ A,
                                                  const float* __restrict__ B,
                                                  const float* __restrict__ F,
                                                  __bf16* __restrict__ fkb) {
    __shared__ __bf16 Xs[32 * 40];    // 32 rows x 32 K-cols, stride 40
    __shared__ __bf16 Fs[128 * 40];   // 128 feat-rows x 32 K-cols

    const int t    = threadIdx.x;
    const int m0   = blockIdx.x * 32;
    const float* src = (m0 < NA) ? (A + (size_t)m0 * KD)
                                 : (B + (size_t)(m0 - NA) * KD);

    const int lane = t & 63;
    const int w    = t >> 6;
    const int ln   = lane & 15;
    const int quad = lane >> 4;
    const int q8   = quad * 8;

    floatx4 acc[2][2];
#pragma unroll
    for (int mt = 0; mt < 2; mt++)
#pragma unroll
        for (int nt = 0; nt < 2; nt++)
            acc[mt][nt] = (floatx4){0.f, 0.f, 0.f, 0.f};

    const int xrow = t >> 3, xcol = (t & 7) * 4;    // 32 rows x 32 cols, 4 floats/thread
    const int frow = t >> 1, fcol = (t & 1) * 16;   // 128 rows x 32 cols, 16 floats/thread
    const float* xp = src + (size_t)xrow * KD + xcol;
    const float* fp = F   + (size_t)frow * KD + fcol;

    // register prefetch of kk=0
    float4 xu = *(const float4*)(xp + 0);
    float4 f0 = *(const float4*)(fp + 0);
    float4 f1 = *(const float4*)(fp + 4);
    float4 f2 = *(const float4*)(fp + 8);
    float4 f3 = *(const float4*)(fp + 12);

#pragma unroll 4
    for (int kk = 0; kk < KD; kk += 32) {
        *(bf16x4*)&Xs[xrow * 40 + xcol]     = cvt4(xu);
        *(bf16x8*)&Fs[frow * 40 + fcol]     = cvt8(f0, f1);
        *(bf16x8*)&Fs[frow * 40 + fcol + 8] = cvt8(f2, f3);
        __syncthreads();

        if (kk + 32 < KD) {   // prefetch next K-chunk while MFMAs run
            xu = *(const float4*)(xp + kk + 32);
            f0 = *(const float4*)(fp + kk + 32);
            f1 = *(const float4*)(fp + kk + 36);
            f2 = *(const float4*)(fp + kk + 40);
            f3 = *(const float4*)(fp + kk + 44);
        }

        bf16x8 bfrag[2];
#pragma unroll
        for (int nt = 0; nt < 2; nt++)
            bfrag[nt] = *(const bf16x8*)&Fs[(w * 32 + nt * 16 + ln) * 40 + q8];
#pragma unroll
        for (int mt = 0; mt < 2; mt++) {
            bf16x8 af = *(const bf16x8*)&Xs[(mt * 16 + ln) * 40 + q8];
#pragma unroll
            for (int nt = 0; nt < 2; nt++)
                acc[mt][nt] = __builtin_amdgcn_mfma_f32_16x16x32_bf16(
                    af, bfrag[nt], acc[mt][nt], 0, 0, 0);
        }
        __syncthreads();
    }

    // write final relu'd bf16 fk rows
#pragma unroll
    for (int mt = 0; mt < 2; mt++)
#pragma unroll
        for (int nt = 0; nt < 2; nt++)
#pragma unroll
            for (int r = 0; r < 4; r++) {
                int row = m0 + mt * 16 + quad * 4 + r;
                int col = w * 32 + nt * 16 + ln;
                fkb[(size_t)row * NF + col] = (__bf16)fmaxf(acc[mt][nt][r], 0.f);
            }
}

// ---- gemm2: out[i][j] = sum_f fkb[i][f] * fkb[1024+j][f] (already relu'd) ----
// grid (32,16): 64x32 out tiles; block = 4 waves (2x2 over 32x16 sub-tiles).
__global__ __launch_bounds__(256) void gemm2(const __bf16* __restrict__ fkb,
                                             float* __restrict__ out) {
    __shared__ __bf16 Ps[64 * 136];
    __shared__ __bf16 Qs[32 * 136];

    const int t    = threadIdx.x;
    const int i0   = blockIdx.y * 64;
    const int j0   = blockIdx.x * 32;
    const int lane = t & 63;
    const int w    = t >> 6;
    const int ln   = lane & 15;
    const int quad = lane >> 4;
    const int q8   = quad * 8;

    {   // stage Ps: 64x128 bf16 (each thread 32 cols)
        const int prow = t >> 2, pcol = (t & 3) * 32;
        const __bf16* p = fkb + (size_t)(i0 + prow) * NF + pcol;
#pragma unroll
        for (int c = 0; c < 32; c += 8)
            *(bf16x8*)&Ps[prow * 136 + pcol + c] = *(const bf16x8*)(p + c);
    }
    {   // stage Qs: 32x128 bf16 (each thread 16 cols)
        const int qrow = t >> 3, qcol = (t & 7) * 16;
        const __bf16* q = fkb + (size_t)(NA + j0 + qrow) * NF + qcol;
#pragma unroll
        for (int c = 0; c < 16; c += 8)
            *(bf16x8*)&Qs[qrow * 136 + qcol + c] = *(const bf16x8*)(q + c);
    }
    __syncthreads();

    const int wm = w & 1;   // 2 row-halves of 32
    const int wn = w >> 1;  // 2 col-halves of 16

    floatx4 acc2[2];
    acc2[0] = (floatx4){0.f, 0.f, 0.f, 0.f};
    acc2[1] = (floatx4){0.f, 0.f, 0.f, 0.f};

#pragma unroll
    for (int k0 = 0; k0 < 128; k0 += 32) {
        bf16x8 bfq = *(const bf16x8*)&Qs[(wn * 16 + ln) * 136 + k0 + q8];
#pragma unroll
        for (int mt = 0; mt < 2; mt++) {
            bf16x8 af = *(const bf16x8*)&Ps[(wm * 32 + mt * 16 + ln) * 136 + k0 + q8];
            acc2[mt] = __builtin_amdgcn_mfma_f32_16x16x32_bf16(
                af, bfq, acc2[mt], 0, 0, 0);
        }
    }

#pragma unroll
    for (int mt = 0; mt < 2; mt++)
#pragma unroll
        for (int r = 0; r < 4; r++) {
            int row = i0 + wm * 32 + mt * 16 + quad * 4 + r;
            int col = j0 + wn * 16 + ln;
            out[(size_t)row * 1024 + col] = acc2[mt][r];
        }
}

extern "C" void kernel_launch(void* const* d_in, const int* in_sizes, int n_in,
                              void* d_out, int out_size, void* d_ws, size_t ws_size,
                              hipStream_t stream) {
    const float* a     = (const float*)d_in[0];
    const float* b     = (const float*)d_in[1];
    const float* feats = (const float*)d_in[2];
    float* out = (float*)d_out;

    __bf16* fkb = (__bf16*)d_ws;   // 2048 x 128 bf16, relu'd (512 KB)

    gemm1_full<<<64, 256, 0, stream>>>(a, b, feats, fkb);
    gemm2<<<dim3(32, 16), 256, 0, stream>>>(fkb, out);
}

// Round 4
// 79.884 us; speedup vs baseline: 1.3944x; 1.3944x over previous
//
#include <hip/hip_runtime.h>

// out[1024][1024] = relu(a @ feats^T) @ relu(b @ feats^T)^T
//   a,b: [1024][2048] fp32, feats: [128][2048] fp32, out fp32.
// Pipeline (3 dispatches; split-K for parallelism, small partial buffer):
//   gemm1_part8: grid (64,8) = 32-row M-stripes x 8 K-splits (K=256 each),
//                512 blocks (2/CU) -> fp32 partials part[8][2048][128] (8 MB)
//   reduce_relu: sum 8 partials, relu, cvt -> bf16 fk[2048][128] (512 KB)
//   gemm2      : 64x64 out tiles via MFMA on relu'd bf16 fk
// Lessons baked in: grid.sync (R1) and atomics (R2) both cost more than a
// dispatch; gemm1 must keep its serial K-chain short (R3: 64 iters = 53 us).

typedef __attribute__((ext_vector_type(8))) __bf16 bf16x8;
typedef __attribute__((ext_vector_type(4))) __bf16 bf16x4;
typedef __attribute__((ext_vector_type(4))) float floatx4;

#define KD     2048   // inner K of gemm1
#define NF     128    // feature count = K of gemm2
#define NA     1024   // rows of a (= rows of b = out dim)
#define NPART  8      // K-splits (K=256 each)
#define KSL    256    // K per split
#define FKN    (2048 * 128)

static __device__ inline bf16x8 cvt8(float4 u, float4 v) {
    bf16x8 s;
    s[0] = (__bf16)u.x; s[1] = (__bf16)u.y; s[2] = (__bf16)u.z; s[3] = (__bf16)u.w;
    s[4] = (__bf16)v.x; s[5] = (__bf16)v.y; s[6] = (__bf16)v.z; s[7] = (__bf16)v.w;
    return s;
}

static __device__ inline bf16x4 cvt4(float4 u) {
    bf16x4 s;
    s[0] = (__bf16)u.x; s[1] = (__bf16)u.y; s[2] = (__bf16)u.z; s[3] = (__bf16)u.w;
    return s;
}

// ---- gemm1_part8: part[s][m0:m0+32][0:128] = X[m0:m0+32, s*256:(s+1)*256] . feats^T
// block = 4 waves; wave w covers feat-cols [w*32, w*32+32). 8 K-iters of 32.
__global__ __launch_bounds__(256) void gemm1_part8(const float* __restrict__ A,
                                                   const float* __restrict__ B,
                                                   const float* __restrict__ F,
                                                   float* __restrict__ part) {
    __shared__ __bf16 Xs[32 * 40];    // 32 rows x 32 K-cols, stride 40
    __shared__ __bf16 Fs[128 * 40];   // 128 feat-rows x 32 K-cols

    const int t    = threadIdx.x;
    const int m0   = blockIdx.x * 32;
    const int s    = blockIdx.y;
    const int k0   = s * KSL;
    const float* src = (m0 < NA) ? (A + (size_t)m0 * KD)
                                 : (B + (size_t)(m0 - NA) * KD);

    const int lane = t & 63;
    const int w    = t >> 6;
    const int ln   = lane & 15;
    const int quad = lane >> 4;
    const int q8   = quad * 8;

    floatx4 acc[2][2];
#pragma unroll
    for (int mt = 0; mt < 2; mt++)
#pragma unroll
        for (int nt = 0; nt < 2; nt++)
            acc[mt][nt] = (floatx4){0.f, 0.f, 0.f, 0.f};

    const int xrow = t >> 3, xcol = (t & 7) * 4;    // 32 rows x 32 cols, 4 floats/thr
    const int frow = t >> 1, fcol = (t & 1) * 16;   // 128 rows x 32 cols, 16 floats/thr
    const float* xp = src + (size_t)xrow * KD + (k0 + xcol);
    const float* fp = F   + (size_t)frow * KD + (k0 + fcol);

    // register prefetch of kk=0
    float4 xu = *(const float4*)(xp + 0);
    float4 f0 = *(const float4*)(fp + 0);
    float4 f1 = *(const float4*)(fp + 4);
    float4 f2 = *(const float4*)(fp + 8);
    float4 f3 = *(const float4*)(fp + 12);

#pragma unroll
    for (int kk = 0; kk < KSL; kk += 32) {
        *(bf16x4*)&Xs[xrow * 40 + xcol]     = cvt4(xu);
        *(bf16x8*)&Fs[frow * 40 + fcol]     = cvt8(f0, f1);
        *(bf16x8*)&Fs[frow * 40 + fcol + 8] = cvt8(f2, f3);
        __syncthreads();

        if (kk + 32 < KSL) {   // prefetch next K-chunk while MFMAs run
            xu = *(const float4*)(xp + kk + 32);
            f0 = *(const float4*)(fp + kk + 32);
            f1 = *(const float4*)(fp + kk + 36);
            f2 = *(const float4*)(fp + kk + 40);
            f3 = *(const float4*)(fp + kk + 44);
        }

        bf16x8 bfrag[2];
#pragma unroll
        for (int nt = 0; nt < 2; nt++)
            bfrag[nt] = *(const bf16x8*)&Fs[(w * 32 + nt * 16 + ln) * 40 + q8];
#pragma unroll
        for (int mt = 0; mt < 2; mt++) {
            bf16x8 af = *(const bf16x8*)&Xs[(mt * 16 + ln) * 40 + q8];
#pragma unroll
            for (int nt = 0; nt < 2; nt++)
                acc[mt][nt] = __builtin_amdgcn_mfma_f32_16x16x32_bf16(
                    af, bfrag[nt], acc[mt][nt], 0, 0, 0);
        }
        __syncthreads();
    }

    float* pdst = part + (size_t)s * FKN;
#pragma unroll
    for (int mt = 0; mt < 2; mt++)
#pragma unroll
        for (int nt = 0; nt < 2; nt++)
#pragma unroll
            for (int r = 0; r < 4; r++) {
                int row = m0 + mt * 16 + quad * 4 + r;
                int col = w * 32 + nt * 16 + ln;
                pdst[(size_t)row * NF + col] = acc[mt][nt][r];
            }
}

// ---- reduce_relu: fkb[i] = bf16(relu(sum_s part[s][i])), vectorized x4 ----
__global__ __launch_bounds__(256) void reduce_relu(const float* __restrict__ part,
                                                   __bf16* __restrict__ fkb) {
    int idx = blockIdx.x * 256 + threadIdx.x;   // 65536 threads, 4 floats each
    size_t base = (size_t)idx * 4;
    float4 sum = make_float4(0.f, 0.f, 0.f, 0.f);
#pragma unroll
    for (int s = 0; s < NPART; s++) {
        float4 u = *(const float4*)(part + (size_t)s * FKN + base);
        sum.x += u.x; sum.y += u.y; sum.z += u.z; sum.w += u.w;
    }
    bf16x4 o;
    o[0] = (__bf16)fmaxf(sum.x, 0.f);
    o[1] = (__bf16)fmaxf(sum.y, 0.f);
    o[2] = (__bf16)fmaxf(sum.z, 0.f);
    o[3] = (__bf16)fmaxf(sum.w, 0.f);
    *(bf16x4*)(fkb + base) = o;
}

// ---- gemm2: out[i][j] = sum_f fkb[i][f] * fkb[1024+j][f] (already relu'd) ----
// grid (16,16): 64x64 out tiles; block = 4 waves in 2x2.
__global__ __launch_bounds__(256) void gemm2(const __bf16* __restrict__ fkb,
                                             float* __restrict__ out) {
    __shared__ __bf16 Ps[64 * 136];
    __shared__ __bf16 Qs[64 * 136];

    const int t    = threadIdx.x;
    const int i0   = blockIdx.y * 64;
    const int j0   = blockIdx.x * 64;
    const int lane = t & 63;
    const int w    = t >> 6;
    const int wm   = w & 1;
    const int wn   = w >> 1;
    const int ln   = lane & 15;
    const int quad = lane >> 4;
    const int q8   = quad * 8;

    // stage 64x128 bf16 rows of a_fk and b_fk
    const int prow = t >> 2, pcol = (t & 3) * 32;
    {
        const __bf16* p = fkb + (size_t)(i0 + prow) * NF + pcol;
        const __bf16* q = fkb + (size_t)(NA + j0 + prow) * NF + pcol;
#pragma unroll
        for (int c = 0; c < 32; c += 8) {
            *(bf16x8*)&Ps[prow * 136 + pcol + c] = *(const bf16x8*)(p + c);
            *(bf16x8*)&Qs[prow * 136 + pcol + c] = *(const bf16x8*)(q + c);
        }
    }
    __syncthreads();

    floatx4 acc[2][2];
#pragma unroll
    for (int mt = 0; mt < 2; mt++)
#pragma unroll
        for (int nt = 0; nt < 2; nt++)
            acc[mt][nt] = (floatx4){0.f, 0.f, 0.f, 0.f};

#pragma unroll
    for (int k0 = 0; k0 < 128; k0 += 32) {
        bf16x8 af[2], bf[2];
#pragma unroll
        for (int mt = 0; mt < 2; mt++)
            af[mt] = *(const bf16x8*)&Ps[(wm * 32 + mt * 16 + ln) * 136 + k0 + q8];
#pragma unroll
        for (int nt = 0; nt < 2; nt++)
            bf[nt] = *(const bf16x8*)&Qs[(wn * 32 + nt * 16 + ln) * 136 + k0 + q8];
#pragma unroll
        for (int mt = 0; mt < 2; mt++)
#pragma unroll
            for (int nt = 0; nt < 2; nt++)
                acc[mt][nt] = __builtin_amdgcn_mfma_f32_16x16x32_bf16(
                    af[mt], bf[nt], acc[mt][nt], 0, 0, 0);
    }

#pragma unroll
    for (int mt = 0; mt < 2; mt++)
#pragma unroll
        for (int nt = 0; nt < 2; nt++)
#pragma unroll
            for (int r = 0; r < 4; r++) {
                int row = i0 + wm * 32 + mt * 16 + quad * 4 + r;
                int col = j0 + wn * 32 + nt * 16 + ln;
                out[(size_t)row * 1024 + col] = acc[mt][nt][r];
            }
}

extern "C" void kernel_launch(void* const* d_in, const int* in_sizes, int n_in,
                              void* d_out, int out_size, void* d_ws, size_t ws_size,
                              hipStream_t stream) {
    const float* a     = (const float*)d_in[0];
    const float* b     = (const float*)d_in[1];
    const float* feats = (const float*)d_in[2];
    float* out = (float*)d_out;

    float*   part = (float*)d_ws;                                      // 8 MB fp32 partials
    __bf16*  fkb  = (__bf16*)((char*)d_ws + (size_t)NPART * FKN * 4);  // 512 KB bf16

    gemm1_part8<<<dim3(64, NPART), 256, 0, stream>>>(a, b, feats, part);
    reduce_relu<<<256, 256, 0, stream>>>(part, fkb);
    gemm2<<<dim3(16, 16), 256, 0, stream>>>(fkb, out);
}